// Round 15
// baseline (220.950 us; speedup 1.0000x reference)
//
#include <hip/hip_runtime.h>
#include <hip/hip_fp16.h>

#define EPS 0.01f
#define NCHUNKS2 512
#define BUCKET_SHIFT 8
#define BUCKET_SZ (1 << BUCKET_SHIFT)
#define CAP 6144        // slots per bucket in eb/csr (avg cnt ~4096, 32-sigma headroom)
#define STAGE_CAP 6144  // LDS-staged records in kDeg (== CAP, always fits)

// ---------------- zero bucket cursors ----------------

__global__ void k_zero_cursors(int* __restrict__ gcur, int nbuck) {
    int i = blockIdx.x * blockDim.x + threadIdx.x;
    if (i < nbuck) gcur[i] = 0;
}

// ---------------- single-pass bucketed edge sort (stage->hist->reserve->scatter) --------

__global__ __launch_bounds__(256) void kAC_fused(const int* __restrict__ src,
                                                 const int* __restrict__ dst,
                                                 int* __restrict__ gcur,
                                                 unsigned int* __restrict__ eb,
                                                 int e, int nbuck, int ce) {
    extern __shared__ int lds[];
    int* ss = lds;            // ce
    int* dd = ss + ce;        // ce
    int* hist = dd + ce;      // nbuck
    int* cur = hist + nbuck;  // nbuck
    int b = blockIdx.x, t = threadIdx.x;
    for (int i = t; i < nbuck; i += 256) hist[i] = 0;
    __syncthreads();
    int lo = b * ce, hi = min(lo + ce, e);
    int len = hi - lo;
    if (len > 0) {
        int len4 = len & ~3;
        for (int i = t * 4; i < len4; i += 1024) {
            int4 s4 = *(const int4*)(src + lo + i);
            int4 d4 = *(const int4*)(dst + lo + i);
            *(int4*)(ss + i) = s4;
            *(int4*)(dd + i) = d4;
            atomicAdd(&hist[d4.x >> BUCKET_SHIFT], 1);
            atomicAdd(&hist[d4.y >> BUCKET_SHIFT], 1);
            atomicAdd(&hist[d4.z >> BUCKET_SHIFT], 1);
            atomicAdd(&hist[d4.w >> BUCKET_SHIFT], 1);
        }
        for (int i = len4 + t; i < len; i += 256) {
            int s = src[lo + i], d = dst[lo + i];
            ss[i] = s; dd[i] = d;
            atomicAdd(&hist[d >> BUCKET_SHIFT], 1);
        }
    }
    __syncthreads();
    // reserve a contiguous range per bucket
    for (int i = t; i < nbuck; i += 256) {
        int h = hist[i];
        int base = h ? atomicAdd(&gcur[i], h) : 0;
        cur[i] = i * CAP + base;
    }
    __syncthreads();
    // scatter staged records into reserved ranges
    for (int i = t; i < len; i += 256) {
        int d = dd[i];
        int pos = atomicAdd(&cur[d >> BUCKET_SHIFT], 1);
        eb[pos] = ((unsigned int)(d & (BUCKET_SZ - 1)) << 23) | (unsigned int)ss[i];
    }
}

// Fused: per-bucket edge stage (LDS) -> degree hist -> block scan (1 elem/thread) ->
// degi/dinv/rowstart -> xs prescale -> csr fill. Block 0 zeroes partial.
__global__ __launch_bounds__(256) void kDeg_fill_prescale(const unsigned int* __restrict__ eb,
                                                          const int* __restrict__ gcur,
                                                          const float* __restrict__ x,
                                                          int* __restrict__ degi,
                                                          float* __restrict__ dinv,
                                                          int* __restrict__ rowstart,
                                                          int* __restrict__ csr_src,
                                                          __half* __restrict__ xs,
                                                          float* __restrict__ partial,
                                                          int n, int nbuck) {
    __shared__ __align__(16) unsigned int ebs[STAGE_CAP];
    __shared__ int hist[BUCKET_SZ];  // later reused as csr cursors
    __shared__ int ps[BUCKET_SZ];
    __shared__ float dv[BUCKET_SZ];
    int k = blockIdx.x, t = threadIdx.x;
    if (k == 0 && t < 64) partial[t] = 0.f;
    hist[t] = 0;
    __syncthreads();
    int lo = k * CAP;
    int cnt = min(gcur[k], CAP);
    int cnt4 = cnt & ~3;
    for (int i = t * 4; i < cnt4; i += 1024) {
        uint4 p4 = *(const uint4*)(eb + lo + i);
        *(uint4*)(ebs + i) = p4;
        atomicAdd(&hist[p4.x >> 23], 1);
        atomicAdd(&hist[p4.y >> 23], 1);
        atomicAdd(&hist[p4.z >> 23], 1);
        atomicAdd(&hist[p4.w >> 23], 1);
    }
    for (int i = cnt4 + t; i < cnt; i += 256) {
        unsigned int p = eb[lo + i];
        ebs[i] = p;
        atomicAdd(&hist[p >> 23], 1);
    }
    __syncthreads();
    int a0 = hist[t];
    ps[t] = a0;
    __syncthreads();
    for (int off = 1; off < 256; off <<= 1) {
        int v = (t >= off) ? ps[t - off] : 0;
        __syncthreads();
        ps[t] += v;
        __syncthreads();
    }
    int excl = ps[t] - a0;
    int node0 = k << BUCKET_SHIFT;
    int rs0 = lo + excl;
    float d0 = rsqrtf((float)a0 + 1.0f);
    dv[t] = d0;
    {
        int nd = node0 + t;
        if (nd < n) {
            degi[nd] = a0;
            dinv[nd] = d0;
            rowstart[nd] = rs0;
        }
    }
    __syncthreads();  // all hist reads (a0) done; dv visible
    hist[t] = rs0;    // reuse as csr cursors
    // prescale: xs[node][c] = x[node][c] * dinv[node]  (half2 vectorized)
    {
        const float2* xf2 = (const float2*)x;
        __half2* xs2 = (__half2*)xs;
        for (int i = t; i < BUCKET_SZ * 8; i += 256) {
            int rl = i >> 3;
            int node = node0 + rl;
            if (node < n) {
                float2 vv = xf2[(size_t)node * 8 + (i & 7)];
                float d = dv[rl];
                xs2[(size_t)node * 8 + (i & 7)] = __floats2half2_rn(vv.x * d, vv.y * d);
            }
        }
    }
    __syncthreads();
    // csr fill from staged records
    for (int i = t; i < cnt; i += 256) {
        unsigned int p = ebs[i];
        int dl = (int)(p >> 23);
        int s = (int)(p & 0x7fffffu);
        int pos = atomicAdd(&hist[dl], 1);
        csr_src[pos] = s;
    }
}

// ---------------- fused layer 1: gather16 (half2, 8 chunked slots) + MLP ----------------
// block = 256 threads = 4 waves; 16 nodes per block (4 per wave). Meta-pipelined.

__global__ __launch_bounds__(256) void k_l1_fused(const int* __restrict__ rowstart,
                                                  const int* __restrict__ degi,
                                                  const int* __restrict__ csr_src,
                                                  const float* __restrict__ dinv,
                                                  const __half* __restrict__ xs,
                                                  const float* __restrict__ W1,
                                                  const float* __restrict__ b1,
                                                  const float* __restrict__ W3,
                                                  __half* __restrict__ h2s, int n) {
    __shared__ float w1[16 * 64];
    __shared__ float w3[64 * 32];
    __shared__ float bs[64];
    __shared__ __align__(16) float a[16 * 16];
    __shared__ float z[16 * 64];
    int t = threadIdx.x;
    for (int i = t; i < 16 * 64; i += 256) w1[i] = W1[i];
    for (int i = t; i < 64 * 32; i += 256) w3[i] = W3[i];
    if (t < 64) bs[t] = b1[t];

    int row0 = blockIdx.x * 16;
    int wv = t >> 6;
    int lane = t & 63;
    int c2 = lane & 7;        // half2 column pair (cols 2c2, 2c2+1)
    int slot = lane >> 3;     // 0..7 edge slots (contiguous chunks)
    const __half2* xs2 = (const __half2*)xs;

    int nb = row0 + wv * 4;
    int node = nb;
    int rs_c = 0, dg_c = 0;
    if (node < n) { rs_c = rowstart[node]; dg_c = degi[node]; }
    for (int nid = 0; nid < 4; ++nid) {
        int node_nxt = nb + nid + 1;
        int rs_n = 0, dg_n = 0;
        if (nid < 3 && node_nxt < n) { rs_n = rowstart[node_nxt]; dg_n = degi[node_nxt]; }
        if (node < n) {
            float dn = dinv[node];
            float2 self = __half22float2(xs2[(size_t)node * 8 + c2]);
            const int* sp = csr_src + rs_c;
            int deg = dg_c;
            int L = (deg + 7) >> 3;
            int base = slot * L;
            int end = min(base + L, deg);
            float ax = 0.f, ay = 0.f, bx = 0.f, by = 0.f;
            int k = base;
            for (; k + 2 <= end; k += 2) {
                int s0 = sp[k], s1 = sp[k + 1];
                float2 v0 = __half22float2(xs2[(size_t)s0 * 8 + c2]);
                float2 v1 = __half22float2(xs2[(size_t)s1 * 8 + c2]);
                ax += v0.x; ay += v0.y;
                bx += v1.x; by += v1.y;
            }
            if (k < end) {
                int s0 = sp[k];
                float2 v0 = __half22float2(xs2[(size_t)s0 * 8 + c2]);
                ax += v0.x; ay += v0.y;
            }
            float sx = ax + bx, sy = ay + by;
            sx += __shfl_xor(sx, 8);  sy += __shfl_xor(sy, 8);
            sx += __shfl_xor(sx, 16); sy += __shfl_xor(sy, 16);
            sx += __shfl_xor(sx, 32); sy += __shfl_xor(sy, 32);
            if (slot == 0) {
                int r = wv * 4 + nid;
                ((float2*)(a + r * 16))[c2] = make_float2(dn * (sx + self.x), dn * (sy + self.y));
            }
        }
        node = node_nxt; rs_c = rs_n; dg_c = dg_n;
    }
    __syncthreads();

    // z = relu(a @ W1 + b1)
    for (int i = t; i < 1024; i += 256) {
        int r = i >> 6, c = i & 63;
        float acc = bs[c];
#pragma unroll
        for (int k = 0; k < 16; ++k) acc += a[r * 16 + k] * w1[k * 64 + c];
        z[i] = acc > 0.f ? acc : 0.f;
    }
    __syncthreads();
    // h2s = (z @ W3) * dinv  (fp16, unified [N][32])
    for (int i = t; i < 512; i += 256) {
        int r = i >> 5, c = i & 31;
        float acc = 0.f;
#pragma unroll
        for (int k = 0; k < 64; ++k) acc += z[r * 64 + k] * w3[k * 32 + c];
        int row = row0 + r;
        if (row < n) h2s[(size_t)row * 32 + c] = __float2half(acc * dinv[row]);
    }
}

// ---------------- layer 2 gather (chunked 4 slots, 4-way unroll, meta-pipelined) --------

__global__ __launch_bounds__(256) void k_gather32_stats(const int* __restrict__ rowstart,
                                                        const int* __restrict__ degi,
                                                        const int* __restrict__ csr_src,
                                                        const float* __restrict__ dinv,
                                                        const __half* __restrict__ h2s,
                                                        const float* __restrict__ b3,
                                                        float* __restrict__ out,
                                                        float* __restrict__ partial, int n) {
    int t = threadIdx.x;
    int lane = t & 63;
    int c2 = lane & 15;       // cols 2c2, 2c2+1
    int slot = lane >> 4;     // 0..3 (contiguous chunks)
    const __half2* h2 = (const __half2*)h2s;
    float2 bias = ((const float2*)b3)[c2];
    float s_x = 0.f, s_y = 0.f, q_x = 0.f, q_y = 0.f;

    int node = blockIdx.x * 32 + (t >> 6);
    int rs_c = 0, dg_c = 0;
    if (node < n) { rs_c = rowstart[node]; dg_c = degi[node]; }
    for (int it = 0; it < 8; ++it) {
        int node_nxt = node + 4;
        int rs_n = 0, dg_n = 0;
        if (it < 7 && node_nxt < n) { rs_n = rowstart[node_nxt]; dg_n = degi[node_nxt]; }
        if (node < n) {
            float dn = dinv[node];
            float2 self = __half22float2(h2[(size_t)node * 16 + c2]);
            const int* sp = csr_src + rs_c;
            int deg = dg_c;
            int L = (deg + 3) >> 2;
            int base = slot * L;
            int end = min(base + L, deg);
            float ax = 0.f, ay = 0.f, bx = 0.f, by = 0.f;
            float cx = 0.f, cy = 0.f, dx = 0.f, dy = 0.f;
            int k = base;
            for (; k + 4 <= end; k += 4) {
                int s0 = sp[k], s1 = sp[k + 1], s2 = sp[k + 2], s3 = sp[k + 3];
                float2 v0 = __half22float2(h2[(size_t)s0 * 16 + c2]);
                float2 v1 = __half22float2(h2[(size_t)s1 * 16 + c2]);
                float2 v2 = __half22float2(h2[(size_t)s2 * 16 + c2]);
                float2 v3 = __half22float2(h2[(size_t)s3 * 16 + c2]);
                ax += v0.x; ay += v0.y;
                bx += v1.x; by += v1.y;
                cx += v2.x; cy += v2.y;
                dx += v3.x; dy += v3.y;
            }
            for (; k < end; ++k) {
                int s0 = sp[k];
                float2 v0 = __half22float2(h2[(size_t)s0 * 16 + c2]);
                ax += v0.x; ay += v0.y;
            }
            float sx = (ax + bx) + (cx + dx);
            float sy = (ay + by) + (cy + dy);
            sx += __shfl_xor(sx, 16); sy += __shfl_xor(sy, 16);
            sx += __shfl_xor(sx, 32); sy += __shfl_xor(sy, 32);
            if (slot == 0) {
                float vx = dn * (sx + self.x) + bias.x;
                float vy = dn * (sy + self.y) + bias.y;
                vx = vx > 0.f ? vx : 0.f;
                vy = vy > 0.f ? vy : 0.f;
                ((float2*)(out + (size_t)node * 32))[c2] = make_float2(vx, vy);
                s_x += vx; s_y += vy;
                q_x += vx * vx; q_y += vy * vy;
            }
        }
        node = node_nxt; rs_c = rs_n; dg_c = dg_n;
    }
    __shared__ float ls[128], lq[128];
    int wv = t >> 6;
    if ((t & 63) < 16) {
        ls[wv * 32 + 2 * c2] = s_x;
        ls[wv * 32 + 2 * c2 + 1] = s_y;
        lq[wv * 32 + 2 * c2] = q_x;
        lq[wv * 32 + 2 * c2 + 1] = q_y;
    }
    __syncthreads();
    if (t < 32) {
        float a = 0.f, b = 0.f;
#pragma unroll
        for (int w = 0; w < 4; ++w) {
            a += ls[w * 32 + t];
            b += lq[w * 32 + t];
        }
        atomicAdd(&partial[t], a);
        atomicAdd(&partial[32 + t], b);
    }
}

// ---------------- normalizer: finalize folded into the norm pass ----------------

__global__ void k_norm(float* __restrict__ h, const float* __restrict__ partial, int n) {
    __shared__ __align__(16) float mv[64];  // [0:32) mean, [32:64) inv-std
    int t = threadIdx.x;
    if (t < 32) {
        float invn = 1.0f / (float)n;
        float mean = partial[t] * invn;
        float var = partial[32 + t] * invn - mean * mean;
        var = var > EPS ? var : EPS;
        mv[t] = mean;
        mv[32 + t] = rsqrtf(var);
    }
    __syncthreads();
    int idx = blockIdx.x * blockDim.x + threadIdx.x;  // over N*8 float4s
    if (idx < n * 8) {
        int c4 = idx & 7;
        float4 v = ((float4*)h)[idx];
        float4 m = ((const float4*)mv)[c4];
        float4 iv = ((const float4*)(mv + 32))[c4];
        v.x = (v.x - m.x) * iv.x;
        v.y = (v.y - m.y) * iv.y;
        v.z = (v.z - m.z) * iv.z;
        v.w = (v.w - m.w) * iv.w;
        ((float4*)h)[idx] = v;
    }
}

extern "C" void kernel_launch(void* const* d_in, const int* in_sizes, int n_in,
                              void* d_out, int out_size, void* d_ws, size_t ws_size,
                              hipStream_t stream) {
    const float* x  = (const float*)d_in[0];
    const int* ei   = (const int*)d_in[1];
    const float* W1 = (const float*)d_in[2];
    const float* b1 = (const float*)d_in[3];
    const float* W3 = (const float*)d_in[4];
    const float* b3 = (const float*)d_in[5];

    const int N = in_sizes[0] / 16;
    const int E = in_sizes[1] / 2;
    const int* src = ei;       // edge_index[0]
    const int* dst = ei + E;   // edge_index[1]

    const int NBUCK = (N + BUCKET_SZ - 1) >> BUCKET_SHIFT;  // 391 for N=100000
    int CE = (E + NCHUNKS2 - 1) / NCHUNKS2;
    CE = (CE + 3) & ~3;  // multiple of 4 for int4 loads

    char* ws = (char*)d_ws;
    int*   degi     = (int*)ws;          ws += (size_t)N * 4;
    float* dinv     = (float*)ws;        ws += (size_t)N * 4;
    int*   rowstart = (int*)ws;          ws += (size_t)N * 4;
    int*   gcur     = (int*)ws;          ws += (size_t)NBUCK * 4;
    unsigned int* eb = (unsigned int*)ws; ws += (size_t)NBUCK * CAP * 4;
    int*   csr_src  = (int*)ws;          ws += (size_t)NBUCK * CAP * 4;
    __half* xs      = (__half*)ws;       ws += (size_t)N * 16 * 2;
    __half* h2s     = (__half*)ws;       ws += (size_t)N * 32 * 2;
    float* partial  = (float*)ws;        ws += 64 * 4;

    float* out = (float*)d_out;  // N*32

    // single-pass bucketed edge sort (cursor reservation replaces global scan)
    k_zero_cursors<<<(NBUCK + 255) / 256, 256, 0, stream>>>(gcur, NBUCK);
    const size_t kac_lds = (size_t)(2 * CE + 2 * NBUCK) * 4;
    kAC_fused<<<NCHUNKS2, 256, kac_lds, stream>>>(src, dst, gcur, eb, E, NBUCK, CE);

    // fused: stage bucket edges in LDS -> hist -> scan -> degi/dinv/rowstart
    //        -> xs prescale -> csr fill (+ partial zero)
    kDeg_fill_prescale<<<NBUCK, 256, 0, stream>>>(eb, gcur, x, degi, dinv, rowstart,
                                                  csr_src, xs, partial, N, NBUCK);

    // layer 1: fused gather + MLP (unified fp16 h2s)
    k_l1_fused<<<(N + 15) / 16, 256, 0, stream>>>(rowstart, degi, csr_src, dinv, xs,
                                                  W1, b1, W3, h2s, N);

    // layer 2: unified gather + bias + relu + stats (meta-pipelined)
    k_gather32_stats<<<(N + 31) / 32, 256, 0, stream>>>(rowstart, degi, csr_src, dinv, h2s,
                                                        b3, out, partial, N);

    // normalizer (finalize folded in)
    k_norm<<<(N * 8 + 255) / 256, 256, 0, stream>>>(out, partial, N);
}

// Round 16
// 167.480 us; speedup vs baseline: 1.3193x; 1.3193x over previous
//
#include <hip/hip_runtime.h>
#include <hip/hip_fp16.h>

#define EPS 0.01f
#define SCAN_BS 512
#define NCHUNKS 256
#define BUCKET_SHIFT 8
#define BUCKET_SZ (1 << BUCKET_SHIFT)
#define STAGE_CAP 6144  // avg bucket cnt ~4092 (E/NBUCK); fallback path exists

// ---------------- exclusive scan (3-kernel, n <= 512*512) ----------------

__global__ __launch_bounds__(SCAN_BS) void k_scan_block(const int* __restrict__ in,
                                                        int* __restrict__ out,
                                                        int* __restrict__ bsum, int n) {
    __shared__ int sd[SCAN_BS];
    int t = threadIdx.x;
    int gid = blockIdx.x * SCAN_BS + t;
    int v = (gid < n) ? in[gid] : 0;
    sd[t] = v;
    __syncthreads();
    for (int off = 1; off < SCAN_BS; off <<= 1) {
        int x = (t >= off) ? sd[t - off] : 0;
        __syncthreads();
        sd[t] += x;
        __syncthreads();
    }
    if (gid < n) out[gid] = sd[t] - v;  // exclusive
    if (t == SCAN_BS - 1) bsum[blockIdx.x] = sd[t];
}

__global__ __launch_bounds__(SCAN_BS) void k_scan_tops(int* __restrict__ bsum, int nb) {
    __shared__ int sd[SCAN_BS];
    int t = threadIdx.x;
    int v = (t < nb) ? bsum[t] : 0;
    sd[t] = v;
    __syncthreads();
    for (int off = 1; off < SCAN_BS; off <<= 1) {
        int x = (t >= off) ? sd[t - off] : 0;
        __syncthreads();
        sd[t] += x;
        __syncthreads();
    }
    if (t < nb) bsum[t] = sd[t] - v;  // exclusive
}

__global__ __launch_bounds__(SCAN_BS) void k_scan_add(int* __restrict__ out,
                                                      const int* __restrict__ bsum, int n) {
    int gid = blockIdx.x * SCAN_BS + threadIdx.x;
    if (gid < n) out[gid] += bsum[blockIdx.x];
}

// ---------------- bucketed edge sort ----------------

__global__ __launch_bounds__(256) void kA_bucket_hist(const int* __restrict__ dst,
                                                      int* __restrict__ bh, int e,
                                                      int nbuck, int ce) {
    extern __shared__ int hist[];  // nbuck
    int b = blockIdx.x, t = threadIdx.x;
    for (int i = t; i < nbuck; i += 256) hist[i] = 0;
    __syncthreads();
    int lo = b * ce, hi = min(lo + ce, e);
    int len = hi - lo;
    if (len > 0) {
        int len4 = len & ~3;
        for (int i = t * 4; i < len4; i += 1024) {
            int4 d4 = *(const int4*)(dst + lo + i);
            atomicAdd(&hist[d4.x >> BUCKET_SHIFT], 1);
            atomicAdd(&hist[d4.y >> BUCKET_SHIFT], 1);
            atomicAdd(&hist[d4.z >> BUCKET_SHIFT], 1);
            atomicAdd(&hist[d4.w >> BUCKET_SHIFT], 1);
        }
        for (int i = len4 + t; i < len; i += 256)
            atomicAdd(&hist[dst[lo + i] >> BUCKET_SHIFT], 1);
    }
    __syncthreads();
    for (int i = t; i < nbuck; i += 256) bh[i * NCHUNKS + b] = hist[i];  // [bucket][chunk]
}

__global__ __launch_bounds__(256) void kC_bucket_scatter(const int* __restrict__ src,
                                                         const int* __restrict__ dst,
                                                         const int* __restrict__ bhs,
                                                         unsigned int* __restrict__ eb, int e,
                                                         int nbuck, int ce) {
    extern __shared__ int cur[];  // nbuck
    int b = blockIdx.x, t = threadIdx.x;
    for (int i = t; i < nbuck; i += 256) cur[i] = bhs[i * NCHUNKS + b];
    __syncthreads();
    int lo = b * ce, hi = min(lo + ce, e);
    int len = hi - lo;
    if (len > 0) {
        int len4 = len & ~3;
        for (int i = t * 4; i < len4; i += 1024) {
            int4 s4 = *(const int4*)(src + lo + i);
            int4 d4 = *(const int4*)(dst + lo + i);
            int p0 = atomicAdd(&cur[d4.x >> BUCKET_SHIFT], 1);
            eb[p0] = ((unsigned int)(d4.x & (BUCKET_SZ - 1)) << 23) | (unsigned int)s4.x;
            int p1 = atomicAdd(&cur[d4.y >> BUCKET_SHIFT], 1);
            eb[p1] = ((unsigned int)(d4.y & (BUCKET_SZ - 1)) << 23) | (unsigned int)s4.y;
            int p2 = atomicAdd(&cur[d4.z >> BUCKET_SHIFT], 1);
            eb[p2] = ((unsigned int)(d4.z & (BUCKET_SZ - 1)) << 23) | (unsigned int)s4.z;
            int p3 = atomicAdd(&cur[d4.w >> BUCKET_SHIFT], 1);
            eb[p3] = ((unsigned int)(d4.w & (BUCKET_SZ - 1)) << 23) | (unsigned int)s4.w;
        }
        for (int i = len4 + t; i < len; i += 256) {
            int s = src[lo + i], d = dst[lo + i];
            int pos = atomicAdd(&cur[d >> BUCKET_SHIFT], 1);
            eb[pos] = ((unsigned int)(d & (BUCKET_SZ - 1)) << 23) | (unsigned int)s;
        }
    }
}

// Fused: per-bucket edge stage (LDS) -> degree hist -> block scan (1 elem/thread) ->
// degi/dinv/rowstart -> xs prescale -> csr fill. Block 0 zeroes partial.
__global__ __launch_bounds__(256) void kDeg_fill_prescale(const unsigned int* __restrict__ eb,
                                                          const int* __restrict__ bhs,
                                                          const float* __restrict__ x,
                                                          int* __restrict__ degi,
                                                          float* __restrict__ dinv,
                                                          int* __restrict__ rowstart,
                                                          int* __restrict__ csr_src,
                                                          __half* __restrict__ xs,
                                                          float* __restrict__ partial,
                                                          int n, int nbuck, int e) {
    __shared__ unsigned int ebs[STAGE_CAP];
    __shared__ int hist[BUCKET_SZ];  // later reused as csr cursors
    __shared__ int ps[BUCKET_SZ];
    __shared__ float dv[BUCKET_SZ];
    int k = blockIdx.x, t = threadIdx.x;
    if (k == 0 && t < 64) partial[t] = 0.f;
    hist[t] = 0;
    __syncthreads();
    int lo = bhs[k * NCHUNKS];
    int hi = (k + 1 < nbuck) ? bhs[(k + 1) * NCHUNKS] : e;
    int cnt = hi - lo;
    bool fits = (cnt <= STAGE_CAP);
    for (int i = t; i < cnt; i += 256) {
        unsigned int p = eb[lo + i];
        if (fits) ebs[i] = p;
        atomicAdd(&hist[p >> 23], 1);
    }
    __syncthreads();
    int a0 = hist[t];
    ps[t] = a0;
    __syncthreads();
    for (int off = 1; off < 256; off <<= 1) {
        int v = (t >= off) ? ps[t - off] : 0;
        __syncthreads();
        ps[t] += v;
        __syncthreads();
    }
    int excl = ps[t] - a0;
    int node0 = k << BUCKET_SHIFT;
    int rs0 = lo + excl;
    float d0 = rsqrtf((float)a0 + 1.0f);
    dv[t] = d0;
    {
        int nd = node0 + t;
        if (nd < n) {
            degi[nd] = a0;
            dinv[nd] = d0;
            rowstart[nd] = rs0;
        }
    }
    __syncthreads();  // all hist reads (a0) done; dv visible
    hist[t] = rs0;    // reuse as csr cursors
    // prescale: xs[node][c] = x[node][c] * dinv[node]  (half2 vectorized)
    {
        const float2* xf2 = (const float2*)x;
        __half2* xs2 = (__half2*)xs;
        for (int i = t; i < BUCKET_SZ * 8; i += 256) {
            int rl = i >> 3;
            int node = node0 + rl;
            if (node < n) {
                float2 vv = xf2[(size_t)node * 8 + (i & 7)];
                float d = dv[rl];
                xs2[(size_t)node * 8 + (i & 7)] = __floats2half2_rn(vv.x * d, vv.y * d);
            }
        }
    }
    __syncthreads();
    // csr fill from staged records
    for (int i = t; i < cnt; i += 256) {
        unsigned int p = fits ? ebs[i] : eb[lo + i];
        int dl = (int)(p >> 23);
        int s = (int)(p & 0x7fffffu);
        int pos = atomicAdd(&hist[dl], 1);
        csr_src[pos] = s;
    }
}

// ---------------- fused layer 1: gather16 (half2, 8 chunked slots) + MLP ----------------
// block = 256 threads = 4 waves; 16 nodes per block (4 per wave). Meta-pipelined.

__global__ __launch_bounds__(256) void k_l1_fused(const int* __restrict__ rowstart,
                                                  const int* __restrict__ degi,
                                                  const int* __restrict__ csr_src,
                                                  const float* __restrict__ dinv,
                                                  const __half* __restrict__ xs,
                                                  const float* __restrict__ W1,
                                                  const float* __restrict__ b1,
                                                  const float* __restrict__ W3,
                                                  __half* __restrict__ h2s, int n) {
    __shared__ float w1[16 * 64];
    __shared__ float w3[64 * 32];
    __shared__ float bs[64];
    __shared__ __align__(16) float a[16 * 16];
    __shared__ float z[16 * 64];
    int t = threadIdx.x;
    for (int i = t; i < 16 * 64; i += 256) w1[i] = W1[i];
    for (int i = t; i < 64 * 32; i += 256) w3[i] = W3[i];
    if (t < 64) bs[t] = b1[t];

    int row0 = blockIdx.x * 16;
    int wv = t >> 6;
    int lane = t & 63;
    int c2 = lane & 7;        // half2 column pair (cols 2c2, 2c2+1)
    int slot = lane >> 3;     // 0..7 edge slots (contiguous chunks)
    const __half2* xs2 = (const __half2*)xs;

    int nb = row0 + wv * 4;
    int node = nb;
    int rs_c = 0, dg_c = 0;
    if (node < n) { rs_c = rowstart[node]; dg_c = degi[node]; }
    for (int nid = 0; nid < 4; ++nid) {
        int node_nxt = nb + nid + 1;
        int rs_n = 0, dg_n = 0;
        if (nid < 3 && node_nxt < n) { rs_n = rowstart[node_nxt]; dg_n = degi[node_nxt]; }
        if (node < n) {
            float dn = dinv[node];
            float2 self = __half22float2(xs2[(size_t)node * 8 + c2]);
            const int* sp = csr_src + rs_c;
            int deg = dg_c;
            int L = (deg + 7) >> 3;
            int base = slot * L;
            int end = min(base + L, deg);
            float ax = 0.f, ay = 0.f, bx = 0.f, by = 0.f;
            int k = base;
            for (; k + 2 <= end; k += 2) {
                int s0 = sp[k], s1 = sp[k + 1];
                float2 v0 = __half22float2(xs2[(size_t)s0 * 8 + c2]);
                float2 v1 = __half22float2(xs2[(size_t)s1 * 8 + c2]);
                ax += v0.x; ay += v0.y;
                bx += v1.x; by += v1.y;
            }
            if (k < end) {
                int s0 = sp[k];
                float2 v0 = __half22float2(xs2[(size_t)s0 * 8 + c2]);
                ax += v0.x; ay += v0.y;
            }
            float sx = ax + bx, sy = ay + by;
            sx += __shfl_xor(sx, 8);  sy += __shfl_xor(sy, 8);
            sx += __shfl_xor(sx, 16); sy += __shfl_xor(sy, 16);
            sx += __shfl_xor(sx, 32); sy += __shfl_xor(sy, 32);
            if (slot == 0) {
                int r = wv * 4 + nid;
                ((float2*)(a + r * 16))[c2] = make_float2(dn * (sx + self.x), dn * (sy + self.y));
            }
        }
        node = node_nxt; rs_c = rs_n; dg_c = dg_n;
    }
    __syncthreads();

    // z = relu(a @ W1 + b1)
    for (int i = t; i < 1024; i += 256) {
        int r = i >> 6, c = i & 63;
        float acc = bs[c];
#pragma unroll
        for (int k = 0; k < 16; ++k) acc += a[r * 16 + k] * w1[k * 64 + c];
        z[i] = acc > 0.f ? acc : 0.f;
    }
    __syncthreads();
    // h2s = (z @ W3) * dinv  (fp16, unified [N][32])
    for (int i = t; i < 512; i += 256) {
        int r = i >> 5, c = i & 31;
        float acc = 0.f;
#pragma unroll
        for (int k = 0; k < 64; ++k) acc += z[r * 64 + k] * w3[k * 32 + c];
        int row = row0 + r;
        if (row < n) h2s[(size_t)row * 32 + c] = __float2half(acc * dinv[row]);
    }
}

// ---------------- layer 2 gather (chunked 4 slots, 4-way unroll, meta-pipelined) --------

__global__ __launch_bounds__(256) void k_gather32_stats(const int* __restrict__ rowstart,
                                                        const int* __restrict__ degi,
                                                        const int* __restrict__ csr_src,
                                                        const float* __restrict__ dinv,
                                                        const __half* __restrict__ h2s,
                                                        const float* __restrict__ b3,
                                                        float* __restrict__ out,
                                                        float* __restrict__ partial, int n) {
    int t = threadIdx.x;
    int lane = t & 63;
    int c2 = lane & 15;       // cols 2c2, 2c2+1
    int slot = lane >> 4;     // 0..3 (contiguous chunks)
    const __half2* h2 = (const __half2*)h2s;
    float2 bias = ((const float2*)b3)[c2];
    float s_x = 0.f, s_y = 0.f, q_x = 0.f, q_y = 0.f;

    int node = blockIdx.x * 32 + (t >> 6);
    int rs_c = 0, dg_c = 0;
    if (node < n) { rs_c = rowstart[node]; dg_c = degi[node]; }
    for (int it = 0; it < 8; ++it) {
        int node_nxt = node + 4;
        int rs_n = 0, dg_n = 0;
        if (it < 7 && node_nxt < n) { rs_n = rowstart[node_nxt]; dg_n = degi[node_nxt]; }
        if (node < n) {
            float dn = dinv[node];
            float2 self = __half22float2(h2[(size_t)node * 16 + c2]);
            const int* sp = csr_src + rs_c;
            int deg = dg_c;
            int L = (deg + 3) >> 2;
            int base = slot * L;
            int end = min(base + L, deg);
            float ax = 0.f, ay = 0.f, bx = 0.f, by = 0.f;
            float cx = 0.f, cy = 0.f, dx = 0.f, dy = 0.f;
            int k = base;
            for (; k + 4 <= end; k += 4) {
                int s0 = sp[k], s1 = sp[k + 1], s2 = sp[k + 2], s3 = sp[k + 3];
                float2 v0 = __half22float2(h2[(size_t)s0 * 16 + c2]);
                float2 v1 = __half22float2(h2[(size_t)s1 * 16 + c2]);
                float2 v2 = __half22float2(h2[(size_t)s2 * 16 + c2]);
                float2 v3 = __half22float2(h2[(size_t)s3 * 16 + c2]);
                ax += v0.x; ay += v0.y;
                bx += v1.x; by += v1.y;
                cx += v2.x; cy += v2.y;
                dx += v3.x; dy += v3.y;
            }
            for (; k < end; ++k) {
                int s0 = sp[k];
                float2 v0 = __half22float2(h2[(size_t)s0 * 16 + c2]);
                ax += v0.x; ay += v0.y;
            }
            float sx = (ax + bx) + (cx + dx);
            float sy = (ay + by) + (cy + dy);
            sx += __shfl_xor(sx, 16); sy += __shfl_xor(sy, 16);
            sx += __shfl_xor(sx, 32); sy += __shfl_xor(sy, 32);
            if (slot == 0) {
                float vx = dn * (sx + self.x) + bias.x;
                float vy = dn * (sy + self.y) + bias.y;
                vx = vx > 0.f ? vx : 0.f;
                vy = vy > 0.f ? vy : 0.f;
                ((float2*)(out + (size_t)node * 32))[c2] = make_float2(vx, vy);
                s_x += vx; s_y += vy;
                q_x += vx * vx; q_y += vy * vy;
            }
        }
        node = node_nxt; rs_c = rs_n; dg_c = dg_n;
    }
    __shared__ float ls[128], lq[128];
    int wv = t >> 6;
    if ((t & 63) < 16) {
        ls[wv * 32 + 2 * c2] = s_x;
        ls[wv * 32 + 2 * c2 + 1] = s_y;
        lq[wv * 32 + 2 * c2] = q_x;
        lq[wv * 32 + 2 * c2 + 1] = q_y;
    }
    __syncthreads();
    if (t < 32) {
        float a = 0.f, b = 0.f;
#pragma unroll
        for (int w = 0; w < 4; ++w) {
            a += ls[w * 32 + t];
            b += lq[w * 32 + t];
        }
        atomicAdd(&partial[t], a);
        atomicAdd(&partial[32 + t], b);
    }
}

// ---------------- normalizer: finalize folded into the norm pass ----------------

__global__ void k_norm(float* __restrict__ h, const float* __restrict__ partial, int n) {
    __shared__ __align__(16) float mv[64];  // [0:32) mean, [32:64) inv-std
    int t = threadIdx.x;
    if (t < 32) {
        float invn = 1.0f / (float)n;
        float mean = partial[t] * invn;
        float var = partial[32 + t] * invn - mean * mean;
        var = var > EPS ? var : EPS;
        mv[t] = mean;
        mv[32 + t] = rsqrtf(var);
    }
    __syncthreads();
    int idx = blockIdx.x * blockDim.x + threadIdx.x;  // over N*8 float4s
    if (idx < n * 8) {
        int c4 = idx & 7;
        float4 v = ((float4*)h)[idx];
        float4 m = ((const float4*)mv)[c4];
        float4 iv = ((const float4*)(mv + 32))[c4];
        v.x = (v.x - m.x) * iv.x;
        v.y = (v.y - m.y) * iv.y;
        v.z = (v.z - m.z) * iv.z;
        v.w = (v.w - m.w) * iv.w;
        ((float4*)h)[idx] = v;
    }
}

extern "C" void kernel_launch(void* const* d_in, const int* in_sizes, int n_in,
                              void* d_out, int out_size, void* d_ws, size_t ws_size,
                              hipStream_t stream) {
    const float* x  = (const float*)d_in[0];
    const int* ei   = (const int*)d_in[1];
    const float* W1 = (const float*)d_in[2];
    const float* b1 = (const float*)d_in[3];
    const float* W3 = (const float*)d_in[4];
    const float* b3 = (const float*)d_in[5];

    const int N = in_sizes[0] / 16;
    const int E = in_sizes[1] / 2;
    const int* src = ei;       // edge_index[0]
    const int* dst = ei + E;   // edge_index[1]

    const int NBUCK = (N + BUCKET_SZ - 1) >> BUCKET_SHIFT;  // 391 for N=100000
    int CE = (E + NCHUNKS - 1) / NCHUNKS;
    CE = (CE + 3) & ~3;  // multiple of 4 for int4 loads
    const int BH_TOTAL = NBUCK * NCHUNKS;

    char* ws = (char*)d_ws;
    int*   degi     = (int*)ws;          ws += (size_t)N * 4;
    float* dinv     = (float*)ws;        ws += (size_t)N * 4;
    int*   rowstart = (int*)ws;          ws += (size_t)N * 4;
    int*   bsum2    = (int*)ws;          ws += (size_t)SCAN_BS * 4;
    int*   bh       = (int*)ws;          ws += (size_t)BH_TOTAL * 4;
    int*   bhs      = (int*)ws;          ws += (size_t)BH_TOTAL * 4;
    unsigned int* eb = (unsigned int*)ws; ws += (size_t)E * 4;
    int*   csr_src  = (int*)ws;          ws += (size_t)E * 4;
    __half* xs      = (__half*)ws;       ws += (size_t)N * 16 * 2;
    __half* h2s     = (__half*)ws;       ws += (size_t)N * 32 * 2;
    float* partial  = (float*)ws;        ws += 64 * 4;

    float* out = (float*)d_out;  // N*32

    const int NB2 = (BH_TOTAL + SCAN_BS - 1) / SCAN_BS;

    // bucketed edge sort
    kA_bucket_hist<<<NCHUNKS, 256, NBUCK * 4, stream>>>(dst, bh, E, NBUCK, CE);
    k_scan_block<<<NB2, SCAN_BS, 0, stream>>>(bh, bhs, bsum2, BH_TOTAL);
    k_scan_tops<<<1, SCAN_BS, 0, stream>>>(bsum2, NB2);
    k_scan_add<<<NB2, SCAN_BS, 0, stream>>>(bhs, bsum2, BH_TOTAL);
    kC_bucket_scatter<<<NCHUNKS, 256, NBUCK * 4, stream>>>(src, dst, bhs, eb, E, NBUCK, CE);

    // fused: stage bucket edges in LDS -> hist -> scan -> degi/dinv/rowstart
    //        -> xs prescale -> csr fill (+ partial zero)
    kDeg_fill_prescale<<<NBUCK, 256, 0, stream>>>(eb, bhs, x, degi, dinv, rowstart,
                                                  csr_src, xs, partial, N, NBUCK, E);

    // layer 1: fused gather + MLP (unified fp16 h2s)
    k_l1_fused<<<(N + 15) / 16, 256, 0, stream>>>(rowstart, degi, csr_src, dinv, xs,
                                                  W1, b1, W3, h2s, N);

    // layer 2: unified gather + bias + relu + stats (meta-pipelined)
    k_gather32_stats<<<(N + 31) / 32, 256, 0, stream>>>(rowstart, degi, csr_src, dinv, h2s,
                                                        b3, out, partial, N);

    // normalizer (finalize folded in)
    k_norm<<<(N * 8 + 255) / 256, 256, 0, stream>>>(out, partial, N);
}